// Round 1
// 371.375 us; speedup vs baseline: 1.1584x; 1.1584x over previous
//
#include <hip/hip_runtime.h>

// ---------------------------------------------------------------------------
// GCN, bf16 data-path.
// R9 change: the old CSR build (deg_pos 8-way global atomics) was pinned at
// the measured ~23 G/s atomic-with-return ceiling (67us, VALU 0.2%, occ 23%).
// Replaced the whole build chain with an ATOMIC-FREE bucketed counting sort:
//   hist (LDS histogram, bucket = dst>>7) -> scan_bucket -> scan_tot ->
//   scatter (LDS-ranked, bucket-grouped edges) -> bucket_csr (per-bucket LDS
//   count+scan+place, dinv fused).
// All ranking atomics are LDS-scope (banked, ~100x global atomic rate).
// GEMM (global_load_lds dbuf MFMA), SpMM (byte-offset broadcast gather) and
// head are unchanged from the 429us version.
// ---------------------------------------------------------------------------

typedef unsigned short ushort_t;
typedef unsigned int uint_t;
typedef __attribute__((ext_vector_type(8))) short short8;
typedef __attribute__((ext_vector_type(4))) float floatx4;

static __device__ __forceinline__ ushort_t f2bf(float f) {
    union { float f; uint_t u; } c; c.f = f;
    return (ushort_t)((c.u + 0x8000u) >> 16);
}
static __device__ __forceinline__ float bf2f(ushort_t h) {
    union { uint_t u; float f; } c; c.u = ((uint_t)h) << 16;
    return c.f;
}
static __device__ __forceinline__ float2 up2(uint_t p) {
    union { uint_t u; float f; } lo, hi;
    lo.u = p << 16; hi.u = p & 0xffff0000u;
    return make_float2(lo.f, hi.f);
}
// async global->LDS, 16B per lane; LDS dst = wave-uniform base + lane*16.
static __device__ __forceinline__ void ld_lds16(void* lds, const void* g) {
    __builtin_amdgcn_global_load_lds(
        (const __attribute__((address_space(1))) unsigned int*)g,
        (__attribute__((address_space(3))) unsigned int*)lds, 16, 0, 0);
}

// ------------------------- CSR build (atomic-free) -------------------------
// bucket = dst >> 7  (128 nodes per bucket).  N=100000 -> NB=782 <= NBMAX.
#define NBMAX 800
#define ECAP  4096   // max edges per bucket held in LDS (mean 2046, sigma ~45)

// P1: per-block LDS histogram over buckets. 8 edges/thread, 2048/block.
__global__ __launch_bounds__(256) void hist_kernel(
    const int* __restrict__ dst, int* __restrict__ histG, int E, int NB) {
    __shared__ int h[NBMAX];
    for (int i = threadIdx.x; i < NB; i += 256) h[i] = 0;
    __syncthreads();
    int i8 = (blockIdx.x * 256 + threadIdx.x) * 8;
    if (i8 + 7 < E) {
        int4 d0 = *(const int4*)(dst + i8);
        int4 d1 = *(const int4*)(dst + i8 + 4);
        atomicAdd(&h[d0.x >> 7], 1);
        atomicAdd(&h[d0.y >> 7], 1);
        atomicAdd(&h[d0.z >> 7], 1);
        atomicAdd(&h[d0.w >> 7], 1);
        atomicAdd(&h[d1.x >> 7], 1);
        atomicAdd(&h[d1.y >> 7], 1);
        atomicAdd(&h[d1.z >> 7], 1);
        atomicAdd(&h[d1.w >> 7], 1);
    } else {
        for (int e = i8; e < E; e++) atomicAdd(&h[dst[e] >> 7], 1);
    }
    __syncthreads();
    int* out = histG + (size_t)blockIdx.x * NB;   // [blk][b], coalesced write
    for (int i = threadIdx.x; i < NB; i += 256) out[i] = h[i];
}

// S1: per-bucket exclusive scan across blocks (in place) + bucket totals.
__global__ __launch_bounds__(256) void scan_bucket(
    int* __restrict__ histG, int* __restrict__ totG, int GB, int NB) {
    __shared__ int s[256];
    const int b = blockIdx.x;
    const int t = threadIdx.x;
    int running = 0;
    int nch = (GB + 255) / 256;
    for (int c = 0; c < nch; c++) {
        int j = c * 256 + t;
        int v = (j < GB) ? histG[(size_t)j * NB + b] : 0;
        s[t] = v;
        __syncthreads();
        for (int off = 1; off < 256; off <<= 1) {
            int tmp = (t >= off) ? s[t - off] : 0;
            __syncthreads();
            s[t] += tmp;
            __syncthreads();
        }
        if (j < GB) histG[(size_t)j * NB + b] = s[t] - v + running;
        int ctot = s[255];
        __syncthreads();
        running += ctot;
    }
    if (t == 0) totG[b] = running;
}

// S2: exclusive scan of bucket totals -> bucket bases; bbase[NB] = E.
__global__ void scan_tot(const int* __restrict__ totG, int* __restrict__ bbase,
                         int NB) {
    __shared__ int s[256];
    const int t = threadIdx.x;
    int running = 0;
    int nch = (NB + 255) / 256;
    for (int c = 0; c < nch; c++) {
        int j = c * 256 + t;
        int v = (j < NB) ? totG[j] : 0;
        s[t] = v;
        __syncthreads();
        for (int off = 1; off < 256; off <<= 1) {
            int tmp = (t >= off) ? s[t - off] : 0;
            __syncthreads();
            s[t] += tmp;
            __syncthreads();
        }
        if (j < NB) bbase[j] = s[t] - v + running;
        int ctot = s[255];
        __syncthreads();
        running += ctot;
    }
    if (t == 0) bbase[NB] = running;
}

// P3: scatter edges into bucket-grouped order. Same block/edge mapping as P1,
// positions come from LDS atomicAdd on this block's reserved ranges.
// packed = src | (dst&127)<<17   (src < 2^17, dl 7 bits).
__global__ __launch_bounds__(256) void scatter_kernel(
    const int* __restrict__ src, const int* __restrict__ dst,
    const int* __restrict__ histG, const int* __restrict__ bbase,
    int* __restrict__ packed, int E, int NB) {
    __shared__ int lbase[NBMAX];
    const int* row = histG + (size_t)blockIdx.x * NB;
    for (int i = threadIdx.x; i < NB; i += 256)
        lbase[i] = bbase[i] + row[i];
    __syncthreads();
    int i8 = (blockIdx.x * 256 + threadIdx.x) * 8;
    if (i8 + 7 < E) {
        int4 s0 = *(const int4*)(src + i8);
        int4 s1 = *(const int4*)(src + i8 + 4);
        int4 d0 = *(const int4*)(dst + i8);
        int4 d1 = *(const int4*)(dst + i8 + 4);
        int p;
        p = atomicAdd(&lbase[d0.x >> 7], 1); packed[p] = s0.x | ((d0.x & 127) << 17);
        p = atomicAdd(&lbase[d0.y >> 7], 1); packed[p] = s0.y | ((d0.y & 127) << 17);
        p = atomicAdd(&lbase[d0.z >> 7], 1); packed[p] = s0.z | ((d0.z & 127) << 17);
        p = atomicAdd(&lbase[d0.w >> 7], 1); packed[p] = s0.w | ((d0.w & 127) << 17);
        p = atomicAdd(&lbase[d1.x >> 7], 1); packed[p] = s1.x | ((d1.x & 127) << 17);
        p = atomicAdd(&lbase[d1.y >> 7], 1); packed[p] = s1.y | ((d1.y & 127) << 17);
        p = atomicAdd(&lbase[d1.z >> 7], 1); packed[p] = s1.z | ((d1.z & 127) << 17);
        p = atomicAdd(&lbase[d1.w >> 7], 1); packed[p] = s1.w | ((d1.w & 127) << 17);
    } else {
        for (int e = i8; e < E; e++) {
            int d = dst[e];
            int p = atomicAdd(&lbase[d >> 7], 1);
            packed[p] = src[e] | ((d & 127) << 17);
        }
    }
}

// P4: one block per bucket. Edges to LDS, count 128 node degrees (dinv fused),
// 128-wide scan -> rowptr, second pass -> csr. rowptr[N]=E falls out of the
// last bucket (nodes >= N have zero count).
__global__ __launch_bounds__(256) void bucket_csr(
    const int* __restrict__ packed, const int* __restrict__ bbase,
    int* __restrict__ rowptr, int* __restrict__ csr,
    float* __restrict__ dinv, int N, int NB) {
    __shared__ int ebuf[ECAP];
    __shared__ int cnt[128];
    __shared__ int pl[128];
    __shared__ int s[256];
    const int b = blockIdx.x;
    const int t = threadIdx.x;
    const int lo = bbase[b];
    const int hi = bbase[b + 1];
    int m = hi - lo;
    if (m > ECAP) m = ECAP;   // statistically unreachable (+45 sigma)
    for (int i = t; i < m; i += 256) ebuf[i] = packed[lo + i];
    if (t < 128) cnt[t] = 0;
    __syncthreads();
    for (int i = t; i < m; i += 256) atomicAdd(&cnt[ebuf[i] >> 17], 1);
    __syncthreads();
    const int node0 = b << 7;
    int c = (t < 128) ? cnt[t] : 0;
    if (t < 128 && node0 + t < N)
        dinv[node0 + t] = rsqrtf((float)(c + 1));   // +1 self loop
    s[t] = c;
    __syncthreads();
    for (int off = 1; off < 256; off <<= 1) {
        int tmp = (t >= off) ? s[t - off] : 0;
        __syncthreads();
        s[t] += tmp;
        __syncthreads();
    }
    int excl = s[t] - c;
    if (t < 128) {
        pl[t] = excl;
        if (node0 + t <= N) rowptr[node0 + t] = lo + excl;
    }
    __syncthreads();
    for (int i = t; i < m; i += 256) {
        int e = ebuf[i];
        int p = atomicAdd(&pl[e >> 17], 1);
        csr[lo + p] = e & 0x1FFFF;
    }
}

// --------------- both weight transposes + bf16 convert, one launch ---------
__global__ void wcvt2_kernel(const float* __restrict__ W1, const float* __restrict__ W2,
                             ushort_t* __restrict__ W1t, ushort_t* __restrict__ W2t) {
    int i = blockIdx.x * 256 + threadIdx.x;
    if (i < 256 * 128) {
        int k = i / 128, n = i % 128;
        W1t[n * 256 + k] = f2bf(W1[i]);
    }
    int j = i - 256 * 128;
    if (j >= 0 && j < 128 * 64) {
        int k = j / 64, n = j % 64;
        W2t[n * 128 + k] = f2bf(W2[j]);
    }
}

// ------------------------------ GEMM 1 -------------------------------------
__global__ __launch_bounds__(256) void gemm1_mfma(
    const float* __restrict__ A, const ushort_t* __restrict__ Bt,
    const float* __restrict__ dinv, ushort_t* __restrict__ out, int M) {
    __shared__ float    As[2][128 * 32];   // 16 KB per buf
    __shared__ ushort_t Bs[2][128 * 32];   // 8 KB per buf
    const int tid = threadIdx.x;
    const int l = tid & 63;
    const int wave = tid >> 6;
    const int wm = wave >> 1, wn = wave & 1;
    const int lrow = l & 15, hh = l >> 4;
    const int m0 = blockIdx.x * 128;

    int aslot0[4], aslot1[4], bslot[4];
    #pragma unroll
    for (int mt = 0; mt < 4; mt++) {
        int r = wm * 64 + mt * 16 + lrow;
        int sw = r & 7;
        aslot0[mt] = (r * 8 + ((2 * hh) ^ sw)) * 4;
        aslot1[mt] = (r * 8 + ((2 * hh + 1) ^ sw)) * 4;
    }
    #pragma unroll
    for (int nt = 0; nt < 4; nt++) {
        int nc = wn * 64 + nt * 16 + lrow;
        bslot[nt] = (nc * 4 + (hh ^ ((nc >> 2) & 3))) * 8;
    }

    floatx4 acc[4][4];
    #pragma unroll
    for (int mt = 0; mt < 4; mt++)
        #pragma unroll
        for (int nt = 0; nt < 4; nt++)
            acc[mt][nt] = (floatx4){0.f, 0.f, 0.f, 0.f};

    auto stage = [&](int buf, int k0) {
        #pragma unroll
        for (int i = 0; i < 4; i++) {           // A: 1024 x 16B
            int s = i * 256 + tid;
            int r = s >> 3, cp = s & 7;
            int cg = cp ^ (r & 7);
            int row = m0 + r; if (row >= M) row = M - 1;
            ld_lds16(&As[buf][s * 4], A + (size_t)row * 256 + k0 + cg * 4);
        }
        #pragma unroll
        for (int i = 0; i < 2; i++) {           // B: 512 x 16B
            int s = i * 256 + tid;
            int nn = s >> 2, cp = s & 3;
            int cg = cp ^ ((nn >> 2) & 3);
            ld_lds16(&Bs[buf][s * 8], Bt + (size_t)nn * 256 + k0 + cg * 8);
        }
    };

    stage(0, 0);
    __syncthreads();
    int buf = 0;
    for (int kk = 0; kk < 8; kk++) {
        if (kk < 7) stage(buf ^ 1, (kk + 1) * 32);
        short8 afr[4], bfr[4];
        #pragma unroll
        for (int mt = 0; mt < 4; mt++) {
            float4 u = *(const float4*)&As[buf][aslot0[mt]];
            float4 v = *(const float4*)&As[buf][aslot1[mt]];
            short8 t;
            t[0] = (short)f2bf(u.x); t[1] = (short)f2bf(u.y);
            t[2] = (short)f2bf(u.z); t[3] = (short)f2bf(u.w);
            t[4] = (short)f2bf(v.x); t[5] = (short)f2bf(v.y);
            t[6] = (short)f2bf(v.z); t[7] = (short)f2bf(v.w);
            afr[mt] = t;
        }
        #pragma unroll
        for (int nt = 0; nt < 4; nt++)
            bfr[nt] = *(const short8*)&Bs[buf][bslot[nt]];
        #pragma unroll
        for (int mt = 0; mt < 4; mt++)
            #pragma unroll
            for (int nt = 0; nt < 4; nt++)
                acc[mt][nt] = __builtin_amdgcn_mfma_f32_16x16x32_bf16(
                    afr[mt], bfr[nt], acc[mt][nt], 0, 0, 0);
        __syncthreads();
        buf ^= 1;
    }

    const int r0 = hh * 4;
    #pragma unroll
    for (int mt = 0; mt < 4; mt++) {
        int mbase = m0 + wm * 64 + mt * 16 + r0;
        float4 dv = *(const float4*)&dinv[mbase];   // dinv padded past N
        float d[4] = {dv.x, dv.y, dv.z, dv.w};
        #pragma unroll
        for (int i = 0; i < 4; i++) {
            int m = mbase + i;
            if (m < M) {
                #pragma unroll
                for (int nt = 0; nt < 4; nt++)
                    out[(size_t)m * 128 + wn * 64 + nt * 16 + lrow] =
                        f2bf(acc[mt][nt][i] * d[i]);
            }
        }
    }
}

// ------------------------------ GEMM 2 -------------------------------------
__global__ __launch_bounds__(256) void gemm2_mfma(
    const ushort_t* __restrict__ A, const ushort_t* __restrict__ Bt,
    const float* __restrict__ dinv, ushort_t* __restrict__ out, int M) {
    __shared__ ushort_t As[2][128 * 32];   // 8 KB per buf
    __shared__ ushort_t Bs[2][64 * 32];    // 4 KB per buf
    const int tid = threadIdx.x;
    const int l = tid & 63;
    const int wave = tid >> 6;
    const int wm = wave >> 1, wn = wave & 1;
    const int lrow = l & 15, hh = l >> 4;
    const int m0 = blockIdx.x * 128;

    int aslot[4], bslot[2];
    #pragma unroll
    for (int mt = 0; mt < 4; mt++) {
        int r = wm * 64 + mt * 16 + lrow;
        aslot[mt] = (r * 4 + (hh ^ ((r >> 2) & 3))) * 8;
    }
    #pragma unroll
    for (int nt = 0; nt < 2; nt++) {
        int nc = wn * 32 + nt * 16 + lrow;
        bslot[nt] = (nc * 4 + (hh ^ ((nc >> 2) & 3))) * 8;
    }

    floatx4 acc[4][2];
    #pragma unroll
    for (int mt = 0; mt < 4; mt++)
        #pragma unroll
        for (int nt = 0; nt < 2; nt++)
            acc[mt][nt] = (floatx4){0.f, 0.f, 0.f, 0.f};

    auto stage = [&](int buf, int k0) {
        #pragma unroll
        for (int i = 0; i < 2; i++) {           // A: 512 x 16B
            int s = i * 256 + tid;
            int r = s >> 2, cp = s & 3;
            int cg = cp ^ ((r >> 2) & 3);
            int row = m0 + r; if (row >= M) row = M - 1;
            ld_lds16(&As[buf][s * 8], A + (size_t)row * 128 + k0 + cg * 8);
        }
        {                                        // B: 256 x 16B
            int s = tid;
            int nn = s >> 2, cp = s & 3;
            int cg = cp ^ ((nn >> 2) & 3);
            ld_lds16(&Bs[buf][s * 8], Bt + (size_t)nn * 128 + k0 + cg * 8);
        }
    };

    stage(0, 0);
    __syncthreads();
    int buf = 0;
    for (int kk = 0; kk < 4; kk++) {
        if (kk < 3) stage(buf ^ 1, (kk + 1) * 32);
        short8 afr[4], bfr[2];
        #pragma unroll
        for (int mt = 0; mt < 4; mt++)
            afr[mt] = *(const short8*)&As[buf][aslot[mt]];
        #pragma unroll
        for (int nt = 0; nt < 2; nt++)
            bfr[nt] = *(const short8*)&Bs[buf][bslot[nt]];
        #pragma unroll
        for (int mt = 0; mt < 4; mt++)
            #pragma unroll
            for (int nt = 0; nt < 2; nt++)
                acc[mt][nt] = __builtin_amdgcn_mfma_f32_16x16x32_bf16(
                    afr[mt], bfr[nt], acc[mt][nt], 0, 0, 0);
        __syncthreads();
        buf ^= 1;
    }

    const int r0 = hh * 4;
    #pragma unroll
    for (int mt = 0; mt < 4; mt++) {
        int mbase = m0 + wm * 64 + mt * 16 + r0;
        float4 dv = *(const float4*)&dinv[mbase];
        float d[4] = {dv.x, dv.y, dv.z, dv.w};
        #pragma unroll
        for (int i = 0; i < 4; i++) {
            int m = mbase + i;
            if (m < M) {
                #pragma unroll
                for (int nt = 0; nt < 2; nt++)
                    out[(size_t)m * 64 + wn * 32 + nt * 16 + lrow] =
                        f2bf(acc[mt][nt][i] * d[i]);
            }
        }
    }
}

// ------------------------------ SpMM 1 -------------------------------------
// F=128, bf16 in/out. Byte-row-offset broadcast (csr<<8) to cut addr math.
__global__ __launch_bounds__(256) void spmm_relu128(
    const ushort_t* __restrict__ Mm, const int* __restrict__ rowptr,
    const int* __restrict__ csr, const float* __restrict__ dinv,
    const float* __restrict__ bias, ushort_t* __restrict__ out, int n) {
    int v = (blockIdx.x * 256 + threadIdx.x) >> 6;
    int lane = threadIdx.x & 63;
    if (v >= n) return;
    int jb = rowptr[v], je = rowptr[v + 1];
    int cntn = je - jb;
    const char* Mb = (const char*)Mm;
    const uint_t loff = lane * 4;

    float2 accA = up2(*(const uint_t*)(Mb + ((size_t)v << 8) + loff));  // self
    float2 accB = make_float2(0.f, 0.f);

    for (int base = 0; base < cntn; base += 64) {
        int m = cntn - base; if (m > 64) m = 64;
        int roff = (base + lane < cntn) ? (csr[jb + base + lane] << 8) : 0;
        int jj = 0;
        for (; jj + 16 <= m; jj += 16) {
            uint_t o[16];
            #pragma unroll
            for (int t = 0; t < 16; t++) o[t] = (uint_t)__shfl(roff, jj + t) + loff;
            uint_t p[16];
            #pragma unroll
            for (int t = 0; t < 16; t++) p[t] = *(const uint_t*)(Mb + o[t]);
            #pragma unroll
            for (int t = 0; t < 16; t++) {
                float2 f = up2(p[t]);
                if (t & 1) { accB.x += f.x; accB.y += f.y; }
                else       { accA.x += f.x; accA.y += f.y; }
            }
        }
        for (; jj + 8 <= m; jj += 8) {
            uint_t o[8];
            #pragma unroll
            for (int t = 0; t < 8; t++) o[t] = (uint_t)__shfl(roff, jj + t) + loff;
            uint_t p[8];
            #pragma unroll
            for (int t = 0; t < 8; t++) p[t] = *(const uint_t*)(Mb + o[t]);
            #pragma unroll
            for (int t = 0; t < 8; t++) {
                float2 f = up2(p[t]);
                if (t & 1) { accB.x += f.x; accB.y += f.y; }
                else       { accA.x += f.x; accA.y += f.y; }
            }
        }
        for (; jj < m; jj++) {
            uint_t o = (uint_t)__shfl(roff, jj) + loff;
            float2 f = up2(*(const uint_t*)(Mb + o));
            accA.x += f.x; accA.y += f.y;
        }
    }
    float d = dinv[v];
    float2 bv = *(const float2*)&bias[lane * 2];
    float rx = fmaxf(d * (accA.x + accB.x) + bv.x, 0.f);
    float ry = fmaxf(d * (accA.y + accB.y) + bv.y, 0.f);
    uint_t packed = ((uint_t)f2bf(ry) << 16) | (uint_t)f2bf(rx);
    *(uint_t*)(out + (size_t)v * 128 + lane * 2) = packed;
}

// ------------------------------ SpMM 2 -------------------------------------
// F=64, bf16 in/out. Byte-row-offset broadcast (csr<<7).
__global__ __launch_bounds__(256) void spmm_relu64(
    const ushort_t* __restrict__ Mm, const int* __restrict__ rowptr,
    const int* __restrict__ csr, const float* __restrict__ dinv,
    const float* __restrict__ bias, ushort_t* __restrict__ out, int n) {
    int v = (blockIdx.x * 256 + threadIdx.x) >> 6;
    int lane = threadIdx.x & 63;
    if (v >= n) return;
    int jb = rowptr[v], je = rowptr[v + 1];
    int cntn = je - jb;
    const char* Mb = (const char*)Mm;
    const uint_t loff = lane * 2;

    float accA = bf2f(*(const ushort_t*)(Mb + ((size_t)v << 7) + loff));  // self
    float accB = 0.f;

    for (int base = 0; base < cntn; base += 64) {
        int m = cntn - base; if (m > 64) m = 64;
        int roff = (base + lane < cntn) ? (csr[jb + base + lane] << 7) : 0;
        int jj = 0;
        for (; jj + 16 <= m; jj += 16) {
            uint_t o[16];
            #pragma unroll
            for (int t = 0; t < 16; t++) o[t] = (uint_t)__shfl(roff, jj + t) + loff;
            ushort_t p[16];
            #pragma unroll
            for (int t = 0; t < 16; t++) p[t] = *(const ushort_t*)(Mb + o[t]);
            #pragma unroll
            for (int t = 0; t < 16; t++) {
                if (t & 1) accB += bf2f(p[t]);
                else       accA += bf2f(p[t]);
            }
        }
        for (; jj + 8 <= m; jj += 8) {
            uint_t o[8];
            #pragma unroll
            for (int t = 0; t < 8; t++) o[t] = (uint_t)__shfl(roff, jj + t) + loff;
            ushort_t p[8];
            #pragma unroll
            for (int t = 0; t < 8; t++) p[t] = *(const ushort_t*)(Mb + o[t]);
            #pragma unroll
            for (int t = 0; t < 8; t++) {
                if (t & 1) accB += bf2f(p[t]);
                else       accA += bf2f(p[t]);
            }
        }
        for (; jj < m; jj++) {
            uint_t o = (uint_t)__shfl(roff, jj) + loff;
            accA += bf2f(*(const ushort_t*)(Mb + o));
        }
    }
    float r = fmaxf(dinv[v] * (accA + accB) + bias[lane], 0.f);
    out[(size_t)v * 64 + lane] = f2bf(r);
}

// ------------------------------ head ---------------------------------------
__global__ __launch_bounds__(256) void head_kernel(
    const ushort_t* __restrict__ h2, const float* __restrict__ Wl,
    const float* __restrict__ bl, float* __restrict__ out, int n) {
    __shared__ float Ws[64 * 10];
    __shared__ float bs[10];
    for (int i = threadIdx.x; i < 640; i += 256) Ws[i] = Wl[i];
    if (threadIdx.x < 10) bs[threadIdx.x] = bl[threadIdx.x];
    __syncthreads();
    int v = blockIdx.x * 256 + threadIdx.x;
    if (v >= n) return;
    float acc[10];
    #pragma unroll
    for (int c = 0; c < 10; c++) acc[c] = bs[c];
    const ushort_t* hrow = &h2[(size_t)v * 64];
    #pragma unroll
    for (int k0 = 0; k0 < 64; k0 += 8) {
        short8 hv = *(const short8*)&hrow[k0];
        #pragma unroll
        for (int kk = 0; kk < 8; kk++) {
            float hf = bf2f((ushort_t)hv[kk]);
            #pragma unroll
            for (int c = 0; c < 10; c++)
                acc[c] += hf * Ws[(k0 + kk) * 10 + c];
        }
    }
    float m = acc[0];
    #pragma unroll
    for (int c = 1; c < 10; c++) m = fmaxf(m, acc[c]);
    float s = 0.f;
    #pragma unroll
    for (int c = 0; c < 10; c++) s += expf(acc[c] - m);
    float lse = logf(s);
    #pragma unroll
    for (int c = 0; c < 10; c++) out[(size_t)v * 10 + c] = acc[c] - m - lse;
}

// ------------------------------ launch -------------------------------------
extern "C" void kernel_launch(void* const* d_in, const int* in_sizes, int n_in,
                              void* d_out, int out_size, void* d_ws, size_t ws_size,
                              hipStream_t stream) {
    const float* x   = (const float*)d_in[0];
    const int*   ei  = (const int*)d_in[1];      // int32 (JAX x64 disabled)
    const float* W1  = (const float*)d_in[2];
    const float* b1  = (const float*)d_in[3];
    const float* W2  = (const float*)d_in[4];
    const float* b2  = (const float*)d_in[5];
    const float* Wl  = (const float*)d_in[6];
    const float* bl  = (const float*)d_in[7];
    float*       out = (float*)d_out;

    const int N = in_sizes[0] / 256;   // 100000
    const int E = in_sizes[1] / 2;     // 1600000
    const int* srcI = ei;
    const int* dstI = ei + E;

    const int NB = (N + 127) >> 7;      // 782 buckets (<= NBMAX)
    const int GB = (E + 2047) / 2048;   // 782 edge blocks, 8 edges/thread

    char* ws = (char*)d_ws;
    size_t off = 0;
    auto alloc = [&](size_t bytes) -> void* {
        void* p = ws + off;
        off = (off + bytes + 255) & ~(size_t)255;
        return p;
    };
    int*      histG  = (int*)alloc((size_t)GB * NB * 4);      // ~2.45 MB
    int*      totG   = (int*)alloc((size_t)NB * 4);
    int*      bbase  = (int*)alloc((size_t)(NB + 1) * 4);
    int*      packed = (int*)alloc((size_t)E * 4);            // bucket-grouped edges
    int*      rowptr = (int*)alloc((size_t)(N + 1) * 4);
    float*    dinv   = (float*)alloc((size_t)(N + 128) * 4);  // padded: BM=128 epilogue float4
    int*      csr    = (int*)alloc((size_t)E * 4);
    ushort_t* W1t    = (ushort_t*)alloc((size_t)128 * 256 * 2);
    ushort_t* W2t    = (ushort_t*)alloc((size_t)64 * 128 * 2);
    ushort_t* bufA   = (ushort_t*)alloc((size_t)N * 128 * 2); // M1' / M2' (bf16)
    ushort_t* bufB   = (ushort_t*)alloc((size_t)N * 128 * 2); // h1 / h2 (bf16)

    // ---- atomic-free CSR build ----
    hist_kernel<<<GB, 256, 0, stream>>>(dstI, histG, E, NB);
    scan_bucket<<<NB, 256, 0, stream>>>(histG, totG, GB, NB);
    scan_tot<<<1, 256, 0, stream>>>(totG, bbase, NB);
    scatter_kernel<<<GB, 256, 0, stream>>>(srcI, dstI, histG, bbase, packed, E, NB);
    bucket_csr<<<NB, 256, 0, stream>>>(packed, bbase, rowptr, csr, dinv, N, NB);

    wcvt2_kernel<<<(256 * 128 + 128 * 64 + 255) / 256, 256, 0, stream>>>(W1, W2, W1t, W2t);

    const int gblk = (N + 127) / 128;
    // layer 1
    gemm1_mfma<<<gblk, 256, 0, stream>>>(x, W1t, dinv, bufA, N);
    spmm_relu128<<<(N + 3) / 4, 256, 0, stream>>>(bufA, rowptr, csr, dinv, b1, bufB, N);
    // layer 2
    gemm2_mfma<<<gblk, 256, 0, stream>>>(bufB, W2t, dinv, bufA, N);
    spmm_relu64<<<(N + 3) / 4, 256, 0, stream>>>(bufA, rowptr, csr, dinv, b2, bufB, N);
    // head
    head_kernel<<<(N + 255) / 256, 256, 0, stream>>>(bufB, Wl, bl, out, N);
}